// Round 3
// baseline (4302.892 us; speedup 1.0000x reference)
//
#include <hip/hip_runtime.h>
#include <hip/hip_bf16.h>
#include <cstdint>
#include <cstddef>

typedef __hip_bfloat16 bf16;
typedef __attribute__((ext_vector_type(8))) short short8;
typedef __attribute__((ext_vector_type(4))) float floatx4;

__device__ __forceinline__ void gload_lds16(const void* g, void* l) {
  __builtin_amdgcn_global_load_lds(
      (__attribute__((address_space(1))) void*)(uintptr_t)g,
      (__attribute__((address_space(3))) void*)l, 16, 0, 0);
}

__device__ __forceinline__ short f2bbits(float f) {
  bf16 h = __float2bfloat16(f);
  return __builtin_bit_cast(short, h);
}
__device__ __forceinline__ float b2f(short s) {
  return __bfloat162float(__builtin_bit_cast(bf16, s));
}

// ---------------- x (fp32) -> xb (bf16), 8 elems/thread ----------------
__global__ __launch_bounds__(256) void convert_x(const float* __restrict__ x,
                                                 bf16* __restrict__ xb) {
  size_t i = ((size_t)blockIdx.x * 256 + threadIdx.x) * 8;
  float4 f0 = *(const float4*)(x + i);
  float4 f1 = *(const float4*)(x + i + 4);
  short8 r;
  r[0] = f2bbits(f0.x); r[1] = f2bbits(f0.y); r[2] = f2bbits(f0.z); r[3] = f2bbits(f0.w);
  r[4] = f2bbits(f1.x); r[5] = f2bbits(f1.y); r[6] = f2bbits(f1.z); r[7] = f2bbits(f1.w);
  *(short8*)(xb + i) = r;
}

// -------- W (1024 x cols, row-major fp32) -> dst[n][k] bf16 (transposed) --------
__global__ __launch_bounds__(256) void transpose_w(const float* __restrict__ src,
                                                   bf16* __restrict__ dst, int cols) {
  __shared__ float tile[32][33];
  int n0 = blockIdx.x * 32, k0 = blockIdx.y * 32;
  int tx = threadIdx.x & 31, ty = threadIdx.x >> 5;
#pragma unroll
  for (int i = 0; i < 32; i += 8) {
    int kk = k0 + ty + i, nn = n0 + tx;
    tile[ty + i][tx] = (nn < cols) ? src[(size_t)kk * cols + nn] : 0.0f;
  }
  __syncthreads();
#pragma unroll
  for (int i = 0; i < 32; i += 8) {
    int nn = n0 + ty + i, kk = k0 + tx;
    if (nn < cols) dst[(size_t)nn * 1024 + kk] = __float2bfloat16(tile[tx][ty + i]);
  }
}

// ---------------- 128x128-tile bf16 MFMA GEMM (m97 structure) ----------------
// mode 0: projection epilogue, N=3072 (512 q | 512 k | 1024 v | 1024 g). mode 1: fp32 out.
__global__ __launch_bounds__(256, 2) void gemm128(
    const bf16* __restrict__ A, const bf16* __restrict__ Bt, int K, int mode,
    float* __restrict__ oq, float* __restrict__ okk, bf16* __restrict__ ov,
    bf16* __restrict__ ogg, float* __restrict__ oo) {
  __shared__ __align__(16) bf16 sA[128 * 32];
  __shared__ __align__(16) bf16 sB[128 * 32];
  const int tid = threadIdx.x;
  const int wave = tid >> 6, lane = tid & 63;
  const int n0 = blockIdx.x * 128, m0 = blockIdx.y * 128;
  const int wm = (wave & 1) * 64, wn = (wave >> 1) * 64;
  const int srow = lane >> 2, scol = (lane & 3) * 8;
  floatx4 acc[4][4] = {};
  const int kIters = K >> 5;
  for (int kt = 0; kt < kIters; ++kt) {
    if (kt) __syncthreads();
    const int kO = (kt << 5) + scol;
#pragma unroll
    for (int c2 = 0; c2 < 2; ++c2) {
      const int chunk = wave * 2 + c2;
      gload_lds16(A + (size_t)(m0 + chunk * 16 + srow) * K + kO, &sA[chunk * 512]);
      gload_lds16(Bt + (size_t)(n0 + chunk * 16 + srow) * K + kO, &sB[chunk * 512]);
    }
    __syncthreads();
    const int l15 = lane & 15, q8 = (lane >> 4) * 8;
    short8 af[4], bfr[4];
#pragma unroll
    for (int i = 0; i < 4; ++i) af[i] = *(const short8*)&sA[(wm + i * 16 + l15) * 32 + q8];
#pragma unroll
    for (int j = 0; j < 4; ++j) bfr[j] = *(const short8*)&sB[(wn + j * 16 + l15) * 32 + q8];
#pragma unroll
    for (int i = 0; i < 4; ++i)
#pragma unroll
      for (int j = 0; j < 4; ++j)
        acc[i][j] = __builtin_amdgcn_mfma_f32_16x16x32_bf16(af[i], bfr[j], acc[i][j], 0, 0, 0);
  }
  const int l15 = lane & 15, rq = (lane >> 4) * 4;
#pragma unroll
  for (int i = 0; i < 4; ++i) {
#pragma unroll
    for (int j = 0; j < 4; ++j) {
      const int n = n0 + wn + j * 16 + l15;
#pragma unroll
      for (int r = 0; r < 4; ++r) {
        const int m = m0 + wm + i * 16 + rq + r;
        const float val = acc[i][j][r];
        if (mode == 1) {
          oo[(size_t)m * 1024 + n] = val;
        } else {
          if (n < 512)       oq[(size_t)m * 512 + n] = val * 0.08838834764831845f;
          else if (n < 1024) okk[(size_t)m * 512 + (n - 512)] = val;
          else if (n < 2048) ov[(size_t)m * 1024 + (n - 1024)] = __float2bfloat16(val);
          else               ogg[(size_t)m * 1024 + (n - 2048)] = __float2bfloat16(val);
        }
      }
    }
  }
}

// ------------- gk = log_sigmoid((x @ w1) @ w2 + b2) / 16, log-space out -------------
__global__ __launch_bounds__(256) void gate_decay2(const float* __restrict__ x,
                                                   const float* __restrict__ w1,
                                                   const float* __restrict__ w2,
                                                   const float* __restrict__ b2,
                                                   float* __restrict__ gkout) {
  __shared__ float sp[256];
  __shared__ float sz[16];
  const int m = blockIdx.x, tid = threadIdx.x;
  const int j = tid & 15, dpart = tid >> 4;
  const float* xr = x + (size_t)m * 1024 + dpart * 64;
  float acc = 0.f;
#pragma unroll 8
  for (int e = 0; e < 64; ++e) acc = fmaf(xr[e], w1[(dpart * 64 + e) * 16 + j], acc);
  sp[tid] = acc;
  __syncthreads();
  if (tid < 16) {
    float s = 0.f;
#pragma unroll
    for (int p = 0; p < 16; ++p) s += sp[p * 16 + tid];
    sz[tid] = s;
  }
  __syncthreads();
#pragma unroll
  for (int u = 0; u < 2; ++u) {
    const int n = tid + u * 256;
    float t = b2[n];
#pragma unroll
    for (int jj = 0; jj < 16; ++jj) t = fmaf(sz[jj], w2[jj * 512 + n], t);
    const float ls = fminf(t, 0.f) - log1pf(__expf(-fabsf(t)));
    gkout[(size_t)m * 512 + n] = ls * 0.0625f;
  }
}

// ------------- chunk prep: b=cumsum(gk); Qt=q*e^b, Kt=k*e^-b, Dtot=e^Btot -------------
// block = one chunk (cid = (b*4+h)*64 + c), 128 threads = one k-dim each.
__global__ __launch_bounds__(128) void chunk_prep(
    const float* __restrict__ q, const float* __restrict__ k,
    const float* __restrict__ gk, bf16* __restrict__ qt,
    bf16* __restrict__ kt, float* __restrict__ dtot) {
  const int cid = blockIdx.x;
  const int c = cid & 63, h = (cid >> 6) & 3, b = cid >> 8;
  const int d = threadIdx.x;
  const size_t rowbase = ((size_t)(b * 4096 + c * 64)) * 512 + h * 128 + d;
  const size_t obase = (size_t)cid * 8192 + d;
  float bsum = 0.f;
  for (int i = 0; i < 64; ++i) {
    const size_t src = rowbase + (size_t)i * 512;
    bsum += gk[src];
    qt[obase + (size_t)i * 128] = __float2bfloat16(q[src] * __expf(bsum));
    kt[obase + (size_t)i * 128] = __float2bfloat16(k[src] * __expf(-bsum));
  }
  dtot[cid * 128 + d] = __expf(bsum);
}

// ------------- chunk intra: A=tril(Qt@Kt^T); o_intra=A@V; U^T=V^T@(Kt*Dtot) -------------
// block = one chunk, 256 threads (4 waves). LDS 63 KB.
__global__ __launch_bounds__(256) void chunk_intra(
    const bf16* __restrict__ qt, const bf16* __restrict__ kt,
    const float* __restrict__ dtot, const bf16* __restrict__ v,
    bf16* __restrict__ oi, bf16* __restrict__ ut) {
  __shared__ __align__(16) short lA[64 * 72];       //  9216 B: masked A, bf16
  __shared__ __align__(16) short stg[27648];        // 55296 B union: {Qs,Ks} then {VT,KhT}
  short* sQ = stg;               // 64 x 136
  short* sK = stg + 8704;        // 64 x 136
  short* sVT = stg;              // 256 x 72  (V transposed: [n][j])
  short* sKhT = stg + 18432;     // 128 x 72  (Khat transposed: [d][j])
  const int cid = blockIdx.x;
  const int c = cid & 63, h = (cid >> 6) & 3, b = cid >> 8;
  const int tid = threadIdx.x, wv = tid >> 6, lane = tid & 63;
  const int l15 = lane & 15, q8 = (lane >> 4) * 8, rq = (lane >> 4) * 4;

  // ---- stage Qt, Kt chunks into padded LDS (rows 128 -> 136)
  {
    const int row = tid >> 2, seg = (tid & 3) * 32;
    const size_t src = (size_t)cid * 8192 + row * 128 + seg;
    const short8* qs = (const short8*)(qt + src);
    const short8* ks = (const short8*)(kt + src);
    short8* qd = (short8*)&sQ[row * 136 + seg];
    short8* kd = (short8*)&sK[row * 136 + seg];
#pragma unroll
    for (int t = 0; t < 4; ++t) { qd[t] = qs[t]; kd[t] = ks[t]; }
  }
  __syncthreads();
  // ---- A = tril(Qt @ Kt^T): wave wv handles rows [16wv, 16wv+16), all 64 cols
  {
    short8 af[4];
#pragma unroll
    for (int kf = 0; kf < 4; ++kf)
      af[kf] = *(const short8*)&sQ[(wv * 16 + l15) * 136 + kf * 32 + q8];
#pragma unroll
    for (int nt = 0; nt < 4; ++nt) {
      floatx4 accA = {0.f, 0.f, 0.f, 0.f};
#pragma unroll
      for (int kf = 0; kf < 4; ++kf) {
        short8 bfr = *(const short8*)&sK[(nt * 16 + l15) * 136 + kf * 32 + q8];
        accA = __builtin_amdgcn_mfma_f32_16x16x32_bf16(af[kf], bfr, accA, 0, 0, 0);
      }
#pragma unroll
      for (int r = 0; r < 4; ++r) {
        const int i = wv * 16 + rq + r, jj = nt * 16 + l15;
        lA[i * 72 + jj] = f2bbits(jj <= i ? accA[r] : 0.f);
      }
    }
  }
  __syncthreads();
  // ---- restage: VT [n][j] and KhT [d][j] = Kt^T * Dtot[d]
  {
#pragma unroll
    for (int e = 0; e < 8; ++e) {
      const int idx = tid + e * 256;
      const int jj = idx >> 5, n0 = (idx & 31) * 8;
      short8 vv = *(const short8*)(v + ((size_t)(b * 4096 + c * 64 + jj)) * 1024 + h * 256 + n0);
#pragma unroll
      for (int t = 0; t < 8; ++t) sVT[(n0 + t) * 72 + jj] = vv[t];
    }
#pragma unroll
    for (int e = 0; e < 4; ++e) {
      const int idx = tid + e * 256;
      const int jj = idx >> 4, d0 = (idx & 15) * 8;
      short8 kk = *(const short8*)(kt + (size_t)cid * 8192 + jj * 128 + d0);
#pragma unroll
      for (int t = 0; t < 8; ++t)
        sKhT[(d0 + t) * 72 + jj] = f2bbits(b2f(kk[t]) * dtot[cid * 128 + d0 + t]);
    }
  }
  __syncthreads();
  // ---- o_intra = A @ V  (M=64, N=256, K=64): wave wv -> rows [16wv,16wv+16)
  {
    short8 aA0 = *(const short8*)&lA[(wv * 16 + l15) * 72 + q8];
    short8 aA1 = *(const short8*)&lA[(wv * 16 + l15) * 72 + 32 + q8];
#pragma unroll
    for (int nt = 0; nt < 16; ++nt) {
      short8 b0 = *(const short8*)&sVT[(nt * 16 + l15) * 72 + q8];
      short8 b1 = *(const short8*)&sVT[(nt * 16 + l15) * 72 + 32 + q8];
      floatx4 acc = {0.f, 0.f, 0.f, 0.f};
      acc = __builtin_amdgcn_mfma_f32_16x16x32_bf16(aA0, b0, acc, 0, 0, 0);
      acc = __builtin_amdgcn_mfma_f32_16x16x32_bf16(aA1, b1, acc, 0, 0, 0);
#pragma unroll
      for (int r = 0; r < 4; ++r) {
        const int i = wv * 16 + rq + r;
        oi[(size_t)cid * 16384 + i * 256 + nt * 16 + l15] = __builtin_bit_cast(bf16, f2bbits(acc[r]));
      }
    }
  }
  // ---- U^T = V^T @ Khat (M=256, N=128, K=64): wave wv -> v-rows [64wv, 64wv+64)
  {
    short8 aV[4][2];
#pragma unroll
    for (int mt = 0; mt < 4; ++mt) {
      aV[mt][0] = *(const short8*)&sVT[(wv * 64 + mt * 16 + l15) * 72 + q8];
      aV[mt][1] = *(const short8*)&sVT[(wv * 64 + mt * 16 + l15) * 72 + 32 + q8];
    }
#pragma unroll
    for (int nt = 0; nt < 8; ++nt) {
      short8 b0 = *(const short8*)&sKhT[(nt * 16 + l15) * 72 + q8];
      short8 b1 = *(const short8*)&sKhT[(nt * 16 + l15) * 72 + 32 + q8];
#pragma unroll
      for (int mt = 0; mt < 4; ++mt) {
        floatx4 acc = {0.f, 0.f, 0.f, 0.f};
        acc = __builtin_amdgcn_mfma_f32_16x16x32_bf16(aV[mt][0], b0, acc, 0, 0, 0);
        acc = __builtin_amdgcn_mfma_f32_16x16x32_bf16(aV[mt][1], b1, acc, 0, 0, 0);
#pragma unroll
        for (int r = 0; r < 4; ++r) {
          const int vr = wv * 64 + mt * 16 + rq + r;
          ut[(size_t)cid * 32768 + vr * 128 + nt * 16 + l15] = __builtin_bit_cast(bf16, f2bbits(acc[r]));
        }
      }
    }
  }
}

// ------------- sequential state pass: S fp32 in regs; o = o_intra + Qt@S_prev -------------
// grid (16 cg, 4 h, 8 b) = 512 blocks, 256 thr: dg = tid&15 (8 dims each), cl = tid>>4 (16 cols).
__global__ __launch_bounds__(256, 4) void state_pass(
    const bf16* __restrict__ ut, const bf16* __restrict__ oi,
    const float* __restrict__ dtot, const bf16* __restrict__ qt,
    bf16* __restrict__ opre) {
  const int cg = blockIdx.x, h = blockIdx.y, b = blockIdx.z;
  const int tid = threadIdx.x;
  const int dg = tid & 15, cl = tid >> 4;
  const int vcol = cg * 16 + cl, d0 = dg * 8;
  const int cid0 = (b * 4 + h) * 64;
  float S[8] = {0.f, 0.f, 0.f, 0.f, 0.f, 0.f, 0.f, 0.f};
  for (int c = 0; c < 64; ++c) {
    const int cid = cid0 + c;
    const bf16* qchunk = qt + (size_t)cid * 8192 + d0;
    const bf16* oichunk = oi + (size_t)cid * 16384 + vcol;
    bf16* ochunk = opre + ((size_t)(b * 4096 + c * 64)) * 1024 + h * 256 + vcol;
    // o_inter for all 64 rows of this chunk uses S BEFORE the update (state after chunk c-1)
#pragma unroll 4
    for (int i = 0; i < 64; ++i) {
      short8 qv = *(const short8*)(qchunk + (size_t)i * 128);
      float p0 = b2f(qv[0]) * S[0];
      float p1 = b2f(qv[1]) * S[1];
      p0 = fmaf(b2f(qv[2]), S[2], p0);
      p1 = fmaf(b2f(qv[3]), S[3], p1);
      p0 = fmaf(b2f(qv[4]), S[4], p0);
      p1 = fmaf(b2f(qv[5]), S[5], p1);
      p0 = fmaf(b2f(qv[6]), S[6], p0);
      p1 = fmaf(b2f(qv[7]), S[7], p1);
      float p = p0 + p1;
      p += __shfl_xor(p, 1);
      p += __shfl_xor(p, 2);
      p += __shfl_xor(p, 4);
      p += __shfl_xor(p, 8);
      if (dg == 0) {
        const float o = p + __bfloat162float(oichunk[(size_t)i * 256]);
        ochunk[(size_t)i * 1024] = __float2bfloat16(o);
      }
    }
    // state update: S = Dtot * S + U
    short8 uv = *(const short8*)(ut + (size_t)cid * 32768 + (size_t)vcol * 128 + d0);
    const float4 dt0 = *(const float4*)(dtot + cid * 128 + d0);
    const float4 dt1 = *(const float4*)(dtot + cid * 128 + d0 + 4);
    S[0] = fmaf(dt0.x, S[0], b2f(uv[0]));
    S[1] = fmaf(dt0.y, S[1], b2f(uv[1]));
    S[2] = fmaf(dt0.z, S[2], b2f(uv[2]));
    S[3] = fmaf(dt0.w, S[3], b2f(uv[3]));
    S[4] = fmaf(dt1.x, S[4], b2f(uv[4]));
    S[5] = fmaf(dt1.y, S[5], b2f(uv[5]));
    S[6] = fmaf(dt1.z, S[6], b2f(uv[6]));
    S[7] = fmaf(dt1.w, S[7], b2f(uv[7]));
  }
}

// ---------------- per-head RMSNorm * g_norm_w, then * swish(g) ----------------
__global__ __launch_bounds__(1024) void norm_gate(
    const bf16* __restrict__ o, const bf16* __restrict__ g,
    const float* __restrict__ gnw, bf16* __restrict__ og) {
  __shared__ float sp[16];
  const int tid = threadIdx.x;
  const size_t idx = (size_t)blockIdx.x * 1024 + tid;
  const float f = __bfloat162float(o[idx]);
  float ss = f * f;
#pragma unroll
  for (int mm = 1; mm <= 32; mm <<= 1) ss += __shfl_xor(ss, mm);
  if ((tid & 63) == 0) sp[tid >> 6] = ss;
  __syncthreads();
  const int h4 = (tid >> 8) * 4;
  const float ms = (sp[h4] + sp[h4 + 1] + sp[h4 + 2] + sp[h4 + 3]) * (1.0f / 256.0f);
  const float scale = rsqrtf(ms + 1e-5f) * gnw[tid & 255];
  const float gv = __bfloat162float(g[idx]);
  const float sw = gv * (1.0f / (1.0f + __expf(-gv)));
  og[idx] = __float2bfloat16(f * scale * sw);
}

extern "C" void kernel_launch(void* const* d_in, const int* in_sizes, int n_in,
                              void* d_out, int out_size, void* d_ws, size_t ws_size,
                              hipStream_t stream) {
  const float* x   = (const float*)d_in[0];
  const float* Wq  = (const float*)d_in[1];
  const float* Wk  = (const float*)d_in[2];
  const float* Wv  = (const float*)d_in[3];
  const float* gw1 = (const float*)d_in[4];
  const float* gw2 = (const float*)d_in[5];
  const float* gb2 = (const float*)d_in[6];
  const float* Wg  = (const float*)d_in[7];
  const float* gnw = (const float*)d_in[8];
  const float* Wo  = (const float*)d_in[9];
  float* out = (float*)d_out;

  // workspace carve: 393 MiB total (proven available: 413 MB in R0-R2).
  // Aliasing timeline:
  //   [9,73)Mi  : xb (conv->proj) -> qt[9,41)+kt[41,73) (prep->A2/B) -> ogat (norm->final)
  //   [73,201)Mi: qb+kb (proj->prep) -> ut bf16 (A2->B)
  //   [201,265)Mi: gkb (gate->prep) -> ointra bf16 (A2->B)
  //   [265,329)Mi: vb (proj->A2) -> opre (B->norm)
  const size_t Mi = 1048576;
  uint8_t* w = (uint8_t*)d_ws;
  bf16*  wallT = (bf16*)(w);              // 3072x1024 bf16 = 6 MiB
  bf16*  woT   = (bf16*)(w + 6 * Mi);     // 2 MiB
  float* dtot  = (float*)(w + 8 * Mi);    // 2048x128 fp32 = 1 MiB
  bf16*  xb    = (bf16*)(w + 9 * Mi);
  bf16*  qt    = (bf16*)(w + 9 * Mi);
  bf16*  ktb   = (bf16*)(w + 41 * Mi);
  bf16*  ogat  = (bf16*)(w + 9 * Mi);
  float* qb    = (float*)(w + 73 * Mi);
  float* kb    = (float*)(w + 137 * Mi);
  bf16*  utb   = (bf16*)(w + 73 * Mi);    // 2048x256x128 bf16 = 128 MiB
  float* gkb   = (float*)(w + 201 * Mi);
  bf16*  oib   = (bf16*)(w + 201 * Mi);   // 2048x64x256 bf16 = 64 MiB
  bf16*  vb    = (bf16*)(w + 265 * Mi);
  bf16*  opre  = (bf16*)(w + 265 * Mi);
  bf16*  gb    = (bf16*)(w + 329 * Mi);   // end 393 MiB

  convert_x<<<dim3(16384), 256, 0, stream>>>(x, xb);
  transpose_w<<<dim3(16, 32), 256, 0, stream>>>(Wq, wallT, 512);
  transpose_w<<<dim3(16, 32), 256, 0, stream>>>(Wk, wallT + (size_t)512 * 1024, 512);
  transpose_w<<<dim3(32, 32), 256, 0, stream>>>(Wv, wallT + (size_t)1024 * 1024, 1024);
  transpose_w<<<dim3(32, 32), 256, 0, stream>>>(Wg, wallT + (size_t)2048 * 1024, 1024);
  transpose_w<<<dim3(32, 32), 256, 0, stream>>>(Wo, woT, 1024);
  gemm128<<<dim3(24, 256), 256, 0, stream>>>(xb, wallT, 1024, 0, qb, kb, vb, gb, nullptr);
  gate_decay2<<<dim3(32768), 256, 0, stream>>>(x, gw1, gw2, gb2, gkb);
  chunk_prep<<<dim3(2048), 128, 0, stream>>>(qb, kb, gkb, qt, ktb, dtot);
  chunk_intra<<<dim3(2048), 256, 0, stream>>>(qt, ktb, dtot, vb, oib, utb);
  state_pass<<<dim3(16, 4, 8), 256, 0, stream>>>(utb, oib, dtot, qt, opre);
  norm_gate<<<dim3(32768), 1024, 0, stream>>>(opre, gb, gnw, ogat);
  gemm128<<<dim3(8, 256), 256, 0, stream>>>(ogat, woT, 1024, 1, nullptr, nullptr, nullptr, nullptr, out);
}

// Round 4
// 1227.448 us; speedup vs baseline: 3.5056x; 3.5056x over previous
//
#include <hip/hip_runtime.h>
#include <hip/hip_bf16.h>
#include <cstdint>
#include <cstddef>

typedef __hip_bfloat16 bf16;
typedef __attribute__((ext_vector_type(8))) short short8;
typedef __attribute__((ext_vector_type(4))) float floatx4;

__device__ __forceinline__ void gload_lds16(const void* g, void* l) {
  __builtin_amdgcn_global_load_lds(
      (__attribute__((address_space(1))) void*)(uintptr_t)g,
      (__attribute__((address_space(3))) void*)l, 16, 0, 0);
}

__device__ __forceinline__ short f2bbits(float f) {
  bf16 h = __float2bfloat16(f);
  return __builtin_bit_cast(short, h);
}
__device__ __forceinline__ float b2f(short s) {
  return __bfloat162float(__builtin_bit_cast(bf16, s));
}

// ---------------- x (fp32) -> xb (bf16), 8 elems/thread ----------------
__global__ __launch_bounds__(256) void convert_x(const float* __restrict__ x,
                                                 bf16* __restrict__ xb) {
  size_t i = ((size_t)blockIdx.x * 256 + threadIdx.x) * 8;
  float4 f0 = *(const float4*)(x + i);
  float4 f1 = *(const float4*)(x + i + 4);
  short8 r;
  r[0] = f2bbits(f0.x); r[1] = f2bbits(f0.y); r[2] = f2bbits(f0.z); r[3] = f2bbits(f0.w);
  r[4] = f2bbits(f1.x); r[5] = f2bbits(f1.y); r[6] = f2bbits(f1.z); r[7] = f2bbits(f1.w);
  *(short8*)(xb + i) = r;
}

// -------- W (1024 x cols, row-major fp32) -> dst[n][k] bf16 (transposed) --------
__global__ __launch_bounds__(256) void transpose_w(const float* __restrict__ src,
                                                   bf16* __restrict__ dst, int cols) {
  __shared__ float tile[32][33];
  int n0 = blockIdx.x * 32, k0 = blockIdx.y * 32;
  int tx = threadIdx.x & 31, ty = threadIdx.x >> 5;
#pragma unroll
  for (int i = 0; i < 32; i += 8) {
    int kk = k0 + ty + i, nn = n0 + tx;
    tile[ty + i][tx] = (nn < cols) ? src[(size_t)kk * cols + nn] : 0.0f;
  }
  __syncthreads();
#pragma unroll
  for (int i = 0; i < 32; i += 8) {
    int nn = n0 + ty + i, kk = k0 + tx;
    if (nn < cols) dst[(size_t)nn * 1024 + kk] = __float2bfloat16(tile[tx][ty + i]);
  }
}

// ---------------- 128x128-tile bf16 MFMA GEMM (m97 structure) ----------------
// mode 0: projection epilogue, N=3072 (512 q | 512 k | 1024 v | 1024 g). mode 1: fp32 out.
__global__ __launch_bounds__(256, 2) void gemm128(
    const bf16* __restrict__ A, const bf16* __restrict__ Bt, int K, int mode,
    float* __restrict__ oq, float* __restrict__ okk, bf16* __restrict__ ov,
    bf16* __restrict__ ogg, float* __restrict__ oo) {
  __shared__ __align__(16) bf16 sA[128 * 32];
  __shared__ __align__(16) bf16 sB[128 * 32];
  const int tid = threadIdx.x;
  const int wave = tid >> 6, lane = tid & 63;
  const int n0 = blockIdx.x * 128, m0 = blockIdx.y * 128;
  const int wm = (wave & 1) * 64, wn = (wave >> 1) * 64;
  const int srow = lane >> 2, scol = (lane & 3) * 8;
  floatx4 acc[4][4] = {};
  const int kIters = K >> 5;
  for (int kt = 0; kt < kIters; ++kt) {
    if (kt) __syncthreads();
    const int kO = (kt << 5) + scol;
#pragma unroll
    for (int c2 = 0; c2 < 2; ++c2) {
      const int chunk = wave * 2 + c2;
      gload_lds16(A + (size_t)(m0 + chunk * 16 + srow) * K + kO, &sA[chunk * 512]);
      gload_lds16(Bt + (size_t)(n0 + chunk * 16 + srow) * K + kO, &sB[chunk * 512]);
    }
    __syncthreads();
    const int l15 = lane & 15, q8 = (lane >> 4) * 8;
    short8 af[4], bfr[4];
#pragma unroll
    for (int i = 0; i < 4; ++i) af[i] = *(const short8*)&sA[(wm + i * 16 + l15) * 32 + q8];
#pragma unroll
    for (int j = 0; j < 4; ++j) bfr[j] = *(const short8*)&sB[(wn + j * 16 + l15) * 32 + q8];
#pragma unroll
    for (int i = 0; i < 4; ++i)
#pragma unroll
      for (int j = 0; j < 4; ++j)
        acc[i][j] = __builtin_amdgcn_mfma_f32_16x16x32_bf16(af[i], bfr[j], acc[i][j], 0, 0, 0);
  }
  const int l15 = lane & 15, rq = (lane >> 4) * 4;
#pragma unroll
  for (int i = 0; i < 4; ++i) {
#pragma unroll
    for (int j = 0; j < 4; ++j) {
      const int n = n0 + wn + j * 16 + l15;
#pragma unroll
      for (int r = 0; r < 4; ++r) {
        const int m = m0 + wm + i * 16 + rq + r;
        const float val = acc[i][j][r];
        if (mode == 1) {
          oo[(size_t)m * 1024 + n] = val;
        } else {
          if (n < 512)       oq[(size_t)m * 512 + n] = val * 0.08838834764831845f;
          else if (n < 1024) okk[(size_t)m * 512 + (n - 512)] = val;
          else if (n < 2048) ov[(size_t)m * 1024 + (n - 1024)] = __float2bfloat16(val);
          else               ogg[(size_t)m * 1024 + (n - 2048)] = __float2bfloat16(val);
        }
      }
    }
  }
}

// ------------- gk = log_sigmoid((x @ w1) @ w2 + b2) / 16, log-space out -------------
__global__ __launch_bounds__(256) void gate_decay2(const float* __restrict__ x,
                                                   const float* __restrict__ w1,
                                                   const float* __restrict__ w2,
                                                   const float* __restrict__ b2,
                                                   float* __restrict__ gkout) {
  __shared__ float sp[256];
  __shared__ float sz[16];
  const int m = blockIdx.x, tid = threadIdx.x;
  const int j = tid & 15, dpart = tid >> 4;
  const float* xr = x + (size_t)m * 1024 + dpart * 64;
  float acc = 0.f;
#pragma unroll 8
  for (int e = 0; e < 64; ++e) acc = fmaf(xr[e], w1[(dpart * 64 + e) * 16 + j], acc);
  sp[tid] = acc;
  __syncthreads();
  if (tid < 16) {
    float s = 0.f;
#pragma unroll
    for (int p = 0; p < 16; ++p) s += sp[p * 16 + tid];
    sz[tid] = s;
  }
  __syncthreads();
#pragma unroll
  for (int u = 0; u < 2; ++u) {
    const int n = tid + u * 256;
    float t = b2[n];
#pragma unroll
    for (int jj = 0; jj < 16; ++jj) t = fmaf(sz[jj], w2[jj * 512 + n], t);
    const float ls = fminf(t, 0.f) - log1pf(__expf(-fabsf(t)));
    gkout[(size_t)m * 512 + n] = ls * 0.0625f;
  }
}

// ------------- chunk prep: b=cumsum(gk); Qt=q*e^b, Kt=k*e^-b, Dtot=e^Btot -------------
__global__ __launch_bounds__(128) void chunk_prep(
    const float* __restrict__ q, const float* __restrict__ k,
    const float* __restrict__ gk, bf16* __restrict__ qt,
    bf16* __restrict__ kt, float* __restrict__ dtot) {
  const int cid = blockIdx.x;
  const int c = cid & 63, h = (cid >> 6) & 3, b = cid >> 8;
  const int d = threadIdx.x;
  const size_t rowbase = ((size_t)(b * 4096 + c * 64)) * 512 + h * 128 + d;
  const size_t obase = (size_t)cid * 8192 + d;
  float bsum = 0.f;
  for (int i = 0; i < 64; ++i) {
    const size_t src = rowbase + (size_t)i * 512;
    bsum += gk[src];
    qt[obase + (size_t)i * 128] = __float2bfloat16(q[src] * __expf(bsum));
    kt[obase + (size_t)i * 128] = __float2bfloat16(k[src] * __expf(-bsum));
  }
  dtot[cid * 128 + d] = __expf(bsum);
}

// ------------- chunk intra: A=tril(Qt@Kt^T); o_intra=A@V; U^T=V^T@(Kt*Dtot) -------------
__global__ __launch_bounds__(256) void chunk_intra(
    const bf16* __restrict__ qt, const bf16* __restrict__ kt,
    const float* __restrict__ dtot, const bf16* __restrict__ v,
    bf16* __restrict__ oi, bf16* __restrict__ ut) {
  __shared__ __align__(16) short lA[64 * 72];
  __shared__ __align__(16) short stg[27648];
  short* sQ = stg;               // 64 x 136
  short* sK = stg + 8704;        // 64 x 136
  short* sVT = stg;              // 256 x 72
  short* sKhT = stg + 18432;     // 128 x 72
  const int cid = blockIdx.x;
  const int c = cid & 63, h = (cid >> 6) & 3, b = cid >> 8;
  const int tid = threadIdx.x, wv = tid >> 6, lane = tid & 63;
  const int l15 = lane & 15, q8 = (lane >> 4) * 8, rq = (lane >> 4) * 4;

  {
    const int row = tid >> 2, seg = (tid & 3) * 32;
    const size_t src = (size_t)cid * 8192 + row * 128 + seg;
    const short8* qs = (const short8*)(qt + src);
    const short8* ks = (const short8*)(kt + src);
    short8* qd = (short8*)&sQ[row * 136 + seg];
    short8* kd = (short8*)&sK[row * 136 + seg];
#pragma unroll
    for (int t = 0; t < 4; ++t) { qd[t] = qs[t]; kd[t] = ks[t]; }
  }
  __syncthreads();
  {
    short8 af[4];
#pragma unroll
    for (int kf = 0; kf < 4; ++kf)
      af[kf] = *(const short8*)&sQ[(wv * 16 + l15) * 136 + kf * 32 + q8];
#pragma unroll
    for (int nt = 0; nt < 4; ++nt) {
      floatx4 accA = {0.f, 0.f, 0.f, 0.f};
#pragma unroll
      for (int kf = 0; kf < 4; ++kf) {
        short8 bfr = *(const short8*)&sK[(nt * 16 + l15) * 136 + kf * 32 + q8];
        accA = __builtin_amdgcn_mfma_f32_16x16x32_bf16(af[kf], bfr, accA, 0, 0, 0);
      }
#pragma unroll
      for (int r = 0; r < 4; ++r) {
        const int i = wv * 16 + rq + r, jj = nt * 16 + l15;
        lA[i * 72 + jj] = f2bbits(jj <= i ? accA[r] : 0.f);
      }
    }
  }
  __syncthreads();
  {
#pragma unroll
    for (int e = 0; e < 8; ++e) {
      const int idx = tid + e * 256;
      const int jj = idx >> 5, n0 = (idx & 31) * 8;
      short8 vv = *(const short8*)(v + ((size_t)(b * 4096 + c * 64 + jj)) * 1024 + h * 256 + n0);
#pragma unroll
      for (int t = 0; t < 8; ++t) sVT[(n0 + t) * 72 + jj] = vv[t];
    }
#pragma unroll
    for (int e = 0; e < 4; ++e) {
      const int idx = tid + e * 256;
      const int jj = idx >> 4, d0 = (idx & 15) * 8;
      short8 kk = *(const short8*)(kt + (size_t)cid * 8192 + jj * 128 + d0);
#pragma unroll
      for (int t = 0; t < 8; ++t)
        sKhT[(d0 + t) * 72 + jj] = f2bbits(b2f(kk[t]) * dtot[cid * 128 + d0 + t]);
    }
  }
  __syncthreads();
  {
    short8 aA0 = *(const short8*)&lA[(wv * 16 + l15) * 72 + q8];
    short8 aA1 = *(const short8*)&lA[(wv * 16 + l15) * 72 + 32 + q8];
#pragma unroll
    for (int nt = 0; nt < 16; ++nt) {
      short8 b0 = *(const short8*)&sVT[(nt * 16 + l15) * 72 + q8];
      short8 b1 = *(const short8*)&sVT[(nt * 16 + l15) * 72 + 32 + q8];
      floatx4 acc = {0.f, 0.f, 0.f, 0.f};
      acc = __builtin_amdgcn_mfma_f32_16x16x32_bf16(aA0, b0, acc, 0, 0, 0);
      acc = __builtin_amdgcn_mfma_f32_16x16x32_bf16(aA1, b1, acc, 0, 0, 0);
#pragma unroll
      for (int r = 0; r < 4; ++r) {
        const int i = wv * 16 + rq + r;
        oi[(size_t)cid * 16384 + i * 256 + nt * 16 + l15] = __builtin_bit_cast(bf16, f2bbits(acc[r]));
      }
    }
  }
  {
    short8 aV[4][2];
#pragma unroll
    for (int mt = 0; mt < 4; ++mt) {
      aV[mt][0] = *(const short8*)&sVT[(wv * 64 + mt * 16 + l15) * 72 + q8];
      aV[mt][1] = *(const short8*)&sVT[(wv * 64 + mt * 16 + l15) * 72 + 32 + q8];
    }
#pragma unroll
    for (int nt = 0; nt < 8; ++nt) {
      short8 b0 = *(const short8*)&sKhT[(nt * 16 + l15) * 72 + q8];
      short8 b1 = *(const short8*)&sKhT[(nt * 16 + l15) * 72 + 32 + q8];
#pragma unroll
      for (int mt = 0; mt < 4; ++mt) {
        floatx4 acc = {0.f, 0.f, 0.f, 0.f};
        acc = __builtin_amdgcn_mfma_f32_16x16x32_bf16(aV[mt][0], b0, acc, 0, 0, 0);
        acc = __builtin_amdgcn_mfma_f32_16x16x32_bf16(aV[mt][1], b1, acc, 0, 0, 0);
#pragma unroll
        for (int r = 0; r < 4; ++r) {
          const int vr = wv * 64 + mt * 16 + rq + r;
          ut[(size_t)cid * 32768 + vr * 128 + nt * 16 + l15] = __builtin_bit_cast(bf16, f2bbits(acc[r]));
        }
      }
    }
  }
}

// ------------- state propagation, IN PLACE over ut -------------
// scb[cid] = S_pre(chunk cid) overwrites U(cid) after it is consumed.
// grid (8 ng, 4 h, 8 b) = 256 blocks; thread owns 16 fp32 states (2 short8 spans).
// Only sequential kernel left: 64 steps, next-chunk U prefetched.
__global__ __launch_bounds__(256) void state_prop(
    bf16* __restrict__ su,          // in: U^T per chunk; out: S_pre per chunk
    const float* __restrict__ dtot) {
  const int ng = blockIdx.x, h = blockIdx.y, b = blockIdx.z;
  const int tid = threadIdx.x;
  const int nrow = ng * 32 + (tid >> 3), kseg = (tid & 7) * 16;
  const int cid0 = (b * 4 + h) * 64;
  const size_t off = (size_t)nrow * 128 + kseg;
  size_t a = (size_t)cid0 * 32768 + off;
  float S[16];
#pragma unroll
  for (int e = 0; e < 16; ++e) S[e] = 0.f;
  short8 u0 = *(const short8*)(su + a);
  short8 u1 = *(const short8*)(su + a + 8);
  for (int c = 0; c < 64; ++c) {
    short8 un0, un1;
    if (c < 63) {
      un0 = *(const short8*)(su + a + 32768);
      un1 = *(const short8*)(su + a + 32768 + 8);
    }
    const float4 d0 = *(const float4*)(dtot + (cid0 + c) * 128 + kseg);
    const float4 d1 = *(const float4*)(dtot + (cid0 + c) * 128 + kseg + 4);
    const float4 d2 = *(const float4*)(dtot + (cid0 + c) * 128 + kseg + 8);
    const float4 d3 = *(const float4*)(dtot + (cid0 + c) * 128 + kseg + 12);
    short8 s0, s1;
#pragma unroll
    for (int e = 0; e < 8; ++e) { s0[e] = f2bbits(S[e]); s1[e] = f2bbits(S[8 + e]); }
    *(short8*)(su + a) = s0;       // write S_pre over consumed U
    *(short8*)(su + a + 8) = s1;
    const float dd[16] = {d0.x, d0.y, d0.z, d0.w, d1.x, d1.y, d1.z, d1.w,
                          d2.x, d2.y, d2.z, d2.w, d3.x, d3.y, d3.z, d3.w};
#pragma unroll
    for (int e = 0; e < 8; ++e) S[e] = fmaf(dd[e], S[e], b2f(u0[e]));
#pragma unroll
    for (int e = 0; e < 8; ++e) S[8 + e] = fmaf(dd[8 + e], S[8 + e], b2f(u1[e]));
    u0 = un0; u1 = un1;
    a += 32768;
  }
}

// ------------- o_inter: opre = oi + Qt @ S_pre  (per chunk, MFMA) -------------
// block = one chunk, 4 waves; wave wv -> v-cols [64wv, 64wv+64). K=128.
__global__ __launch_bounds__(256, 2) void o_inter(
    const bf16* __restrict__ qt, const bf16* __restrict__ scb,
    const bf16* __restrict__ oi, bf16* __restrict__ opre) {
  __shared__ __align__(16) short sQ[64 * 136];
  const int cid = blockIdx.x;
  const int c = cid & 63, h = (cid >> 6) & 3, b = cid >> 8;
  const int tid = threadIdx.x, wv = tid >> 6, lane = tid & 63;
  const int l15 = lane & 15, q8 = (lane >> 4) * 8, rq = (lane >> 4) * 4;
  {
    const int row = tid >> 2, seg = (tid & 3) * 32;
    const short8* qs = (const short8*)(qt + (size_t)cid * 8192 + row * 128 + seg);
    short8* qd = (short8*)&sQ[row * 136 + seg];
#pragma unroll
    for (int t = 0; t < 4; ++t) qd[t] = qs[t];
  }
  __syncthreads();
  short8 af[4][4];
#pragma unroll
  for (int i = 0; i < 4; ++i)
#pragma unroll
    for (int kf = 0; kf < 4; ++kf)
      af[i][kf] = *(const short8*)&sQ[(i * 16 + l15) * 136 + kf * 32 + q8];
  floatx4 acc[4][4] = {};
#pragma unroll
  for (int j = 0; j < 4; ++j) {
#pragma unroll
    for (int kf = 0; kf < 4; ++kf) {
      short8 bfr = *(const short8*)(scb + (size_t)cid * 32768 +
                                    (size_t)(wv * 64 + j * 16 + l15) * 128 + kf * 32 + q8);
#pragma unroll
      for (int i = 0; i < 4; ++i)
        acc[i][j] = __builtin_amdgcn_mfma_f32_16x16x32_bf16(af[i][kf], bfr, acc[i][j], 0, 0, 0);
    }
  }
  const size_t rowg0 = (size_t)(b * 4096 + c * 64);
#pragma unroll
  for (int i = 0; i < 4; ++i) {
#pragma unroll
    for (int j = 0; j < 4; ++j) {
      const int col = wv * 64 + j * 16 + l15;
#pragma unroll
      for (int r = 0; r < 4; ++r) {
        const int row = i * 16 + rq + r;
        const float val = acc[i][j][r] +
            __bfloat162float(oi[(size_t)cid * 16384 + row * 256 + col]);
        opre[(rowg0 + row) * 1024 + h * 256 + col] = __float2bfloat16(val);
      }
    }
  }
}

// ---------------- per-head RMSNorm * g_norm_w, then * swish(g) ----------------
__global__ __launch_bounds__(1024) void norm_gate(
    const bf16* __restrict__ o, const bf16* __restrict__ g,
    const float* __restrict__ gnw, bf16* __restrict__ og) {
  __shared__ float sp[16];
  const int tid = threadIdx.x;
  const size_t idx = (size_t)blockIdx.x * 1024 + tid;
  const float f = __bfloat162float(o[idx]);
  float ss = f * f;
#pragma unroll
  for (int mm = 1; mm <= 32; mm <<= 1) ss += __shfl_xor(ss, mm);
  if ((tid & 63) == 0) sp[tid >> 6] = ss;
  __syncthreads();
  const int h4 = (tid >> 8) * 4;
  const float ms = (sp[h4] + sp[h4 + 1] + sp[h4 + 2] + sp[h4 + 3]) * (1.0f / 256.0f);
  const float scale = rsqrtf(ms + 1e-5f) * gnw[tid & 255];
  const float gv = __bfloat162float(g[idx]);
  const float sw = gv * (1.0f / (1.0f + __expf(-gv)));
  og[idx] = __float2bfloat16(f * scale * sw);
}

extern "C" void kernel_launch(void* const* d_in, const int* in_sizes, int n_in,
                              void* d_out, int out_size, void* d_ws, size_t ws_size,
                              hipStream_t stream) {
  const float* x   = (const float*)d_in[0];
  const float* Wq  = (const float*)d_in[1];
  const float* Wk  = (const float*)d_in[2];
  const float* Wv  = (const float*)d_in[3];
  const float* gw1 = (const float*)d_in[4];
  const float* gw2 = (const float*)d_in[5];
  const float* gb2 = (const float*)d_in[6];
  const float* Wg  = (const float*)d_in[7];
  const float* gnw = (const float*)d_in[8];
  const float* Wo  = (const float*)d_in[9];
  float* out = (float*)d_out;

  // carve unchanged from R3 (393 MiB); scb == utb (in-place state_prop).
  const size_t Mi = 1048576;
  uint8_t* w = (uint8_t*)d_ws;
  bf16*  wallT = (bf16*)(w);
  bf16*  woT   = (bf16*)(w + 6 * Mi);
  float* dtot  = (float*)(w + 8 * Mi);
  bf16*  xb    = (bf16*)(w + 9 * Mi);
  bf16*  qt    = (bf16*)(w + 9 * Mi);
  bf16*  ktb   = (bf16*)(w + 41 * Mi);
  bf16*  ogat  = (bf16*)(w + 9 * Mi);
  float* qb    = (float*)(w + 73 * Mi);
  float* kb    = (float*)(w + 137 * Mi);
  bf16*  utb   = (bf16*)(w + 73 * Mi);    // U^T then S_pre (in place)
  float* gkb   = (float*)(w + 201 * Mi);
  bf16*  oib   = (bf16*)(w + 201 * Mi);
  bf16*  vb    = (bf16*)(w + 265 * Mi);
  bf16*  opre  = (bf16*)(w + 265 * Mi);
  bf16*  gb    = (bf16*)(w + 329 * Mi);

  convert_x<<<dim3(16384), 256, 0, stream>>>(x, xb);
  transpose_w<<<dim3(16, 32), 256, 0, stream>>>(Wq, wallT, 512);
  transpose_w<<<dim3(16, 32), 256, 0, stream>>>(Wk, wallT + (size_t)512 * 1024, 512);
  transpose_w<<<dim3(32, 32), 256, 0, stream>>>(Wv, wallT + (size_t)1024 * 1024, 1024);
  transpose_w<<<dim3(32, 32), 256, 0, stream>>>(Wg, wallT + (size_t)2048 * 1024, 1024);
  transpose_w<<<dim3(32, 32), 256, 0, stream>>>(Wo, woT, 1024);
  gemm128<<<dim3(24, 256), 256, 0, stream>>>(xb, wallT, 1024, 0, qb, kb, vb, gb, nullptr);
  gate_decay2<<<dim3(32768), 256, 0, stream>>>(x, gw1, gw2, gb2, gkb);
  chunk_prep<<<dim3(2048), 128, 0, stream>>>(qb, kb, gkb, qt, ktb, dtot);
  chunk_intra<<<dim3(2048), 256, 0, stream>>>(qt, ktb, dtot, vb, oib, utb);
  state_prop<<<dim3(8, 4, 8), 256, 0, stream>>>(utb, dtot);
  o_inter<<<dim3(2048), 256, 0, stream>>>(qt, utb, oib, opre);
  norm_gate<<<dim3(32768), 1024, 0, stream>>>(opre, gb, gnw, ogat);
  gemm128<<<dim3(8, 256), 256, 0, stream>>>(ogat, woT, 1024, 1, nullptr, nullptr, nullptr, nullptr, out);
}